// Round 8
// baseline (888.738 us; speedup 1.0000x reference)
//
#include <hip/hip_runtime.h>
#include <math.h>

#define Bq 2
#define NEG 16
#define Nn 10000
#define Ee 80000
#define Dd 128
#define NUM_REL 237
#define Ll 3
#define K_SEL 1000
#define BN (Bq*Nn)
#define EPSV 1e-5f
#define MAXACT 2048
#define MAXTOUCH 8192
#define SELCAP 3328
#define LN2F 0.69314718056f
#define MSG_GRID 512

// ---------------- workspace layout (bytes) ----------------
constexpr size_t HID_OFF   = 0;                                   // BN*D f32
constexpr size_t SCORE_OFF = HID_OFF   + (size_t)BN*Dd*4;         // BN f32
constexpr size_t CVEC_OFF  = SCORE_OFF + (size_t)BN*4;            // B*D f32
constexpr size_t HDR_OFF   = CVEC_OFF  + (size_t)Bq*Dd*4;         // 64 i32
constexpr size_t THR_OFF   = HDR_OFF   + 64*4;                    // B u64
constexpr size_t DEG_OFF   = THR_OFF   + 64*8;                    // BN u32
constexpr size_t SLOT_OFF  = DEG_OFF   + (size_t)BN*4;            // BN i32
constexpr size_t CNT_OFF   = SLOT_OFF  + (size_t)BN*4;            // MAXACT u32
constexpr size_t SDEG_OFF  = CNT_OFF   + (size_t)MAXACT*4;        // MAXACT f32
constexpr size_t S1_OFF    = SDEG_OFF  + (size_t)MAXACT*4;        // MAXACT*D f32
constexpr size_t S2_OFF    = S1_OFF    + (size_t)MAXACT*Dd*4;
constexpr size_t MXB_OFF   = S2_OFF    + (size_t)MAXACT*Dd*4;     // MAXACT*D u32
constexpr size_t MNB_OFF   = MXB_OFF   + (size_t)MAXACT*Dd*4;
constexpr size_t ALIST_OFF = MNB_OFF   + (size_t)MAXACT*Dd*4;     // MAXACT i32
constexpr size_t FLAG_OFF  = ALIST_OFF + (size_t)MAXACT*4;        // BN u32
constexpr size_t TLIST_OFF = FLAG_OFF  + (size_t)BN*4;            // MAXTOUCH i32
constexpr size_t CTR_OFF   = TLIST_OFF + (size_t)MAXTOUCH*4;      // 16 u32
// ctr[0]=na ctr[2]=log-sum f32bits ctr[3]=ntouched ctr[4]=sc0 bits

// ---------------- helpers ----------------
__device__ __forceinline__ unsigned encf(float f){
  unsigned u = __float_as_uint(f);
  return (u & 0x80000000u) ? ~u : (u | 0x80000000u);
}
__device__ __forceinline__ float decf(unsigned e){
  unsigned u = (e & 0x80000000u) ? (e & 0x7FFFFFFFu) : ~e;
  return __uint_as_float(u);
}
__device__ __forceinline__ unsigned long long make_key(float f, int i){
  unsigned d = ~encf(f);
  return ((unsigned long long)d << 32) | (unsigned)i;
}

// ---------------- k_init: zero+fill+boundary+prep ----------------
__global__ __launch_bounds__(256) void k_init(
    const int* h_index, const int* r_index, const int* t_index,
    const float* hidden_states, const float* rel_embedding,
    const float* lin_W, const float* lin_b, const float* m1_W, const float* m1_b,
    const float* m2_W, const float* m2_b,
    int* hdr, float* cvec, float* hidden, float* score,
    unsigned* flag, int* tlist, unsigned* ctr){
  __shared__ int sfh[Bq], sft[Bq], sr0[Bq], shsrc, stsrc;
  __shared__ float sp[Dd];
  __shared__ float ssc0;
  __shared__ float relv[Bq][Dd], cvv[Bq][Dd], hv[Dd], xx[Bq][Dd], pp[Bq][Dd];
  int tid = threadIdx.x;
  if (tid == 0){
    for (int b=0;b<Bq;b++){
      bool eq = true;
      for (int j=1;j<NEG;j++) eq = eq && (h_index[b*NEG+j]==h_index[b*NEG]);
      int h0 = eq ? h_index[b*NEG] : t_index[b*NEG];
      int t0 = eq ? t_index[b*NEG] : h_index[b*NEG];
      int r0 = eq ? r_index[b*NEG] : r_index[b*NEG] + NUM_REL;
      sfh[b] = h0 + b*Nn; sft[b] = t0 + b*Nn; sr0[b] = r0;
      if (b==0){ shsrc = h0; stsrc = t0; }
    }
  }
  if (tid < Dd) sp[tid] = fmaxf(m1_b[tid], 0.f) * m2_W[tid];
  __syncthreads();
  if (tid == 0){
    float s = m2_b[0];
    for (int k=0;k<Dd;k++) s += sp[k];
    ssc0 = s;
  }
  __syncthreads();
  float sc0 = ssc0;
  int fh0 = sfh[0], fh1 = sfh[1], ft0 = sft[0], ft1 = sft[1];
  int gth = blockIdx.x*256 + tid, gstr = gridDim.x*256;
  for (int i = gth; i < BN*Dd/4; i += gstr){
    int row = i >> 5, c4 = i & 31;
    float4 v;
    if (row == fh0 || row == fh1)
      v = ((const float4*)(hidden_states + (size_t)shsrc*Dd))[c4];
    else if (row == ft0 || row == ft1)
      v = ((const float4*)(hidden_states + (size_t)stsrc*Dd))[c4];
    else v = make_float4(0.f,0.f,0.f,0.f);
    ((float4*)hidden)[i] = v;
  }
  for (int i = gth; i < BN; i += gstr){
    flag[i] = (i==fh0 || i==fh1 || i==ft0 || i==ft1) ? 1u : 0u;
    if (i != fh0 && i != fh1) score[i] = sc0;
  }
  if (blockIdx.x == 0){
    if (tid == 0){
      int tl[4]; int n = 0;
      for (int b=0;b<Bq;b++){
        hdr[b] = sfh[b]; hdr[2+b] = sft[b];
        bool eq = true;
        for (int j=1;j<NEG;j++) eq = eq && (h_index[b*NEG+j]==h_index[b*NEG]);
        for (int j=0;j<NEG;j++){
          int tj = eq ? t_index[b*NEG+j] : h_index[b*NEG+j];
          hdr[4 + b*NEG + j] = tj + b*Nn;
        }
        int c1 = sft[b]; bool f1=false;
        for (int q=0;q<n;q++) f1 = f1 || (tl[q]==c1);
        if (!f1) tl[n++] = c1;
        int c2 = sfh[b]; bool f2=false;
        for (int q=0;q<n;q++) f2 = f2 || (tl[q]==c2);
        if (!f2) tl[n++] = c2;
      }
      for (int q=0;q<n;q++) tlist[q] = tl[q];
      ctr[3] = (unsigned)n;
      ctr[4] = __float_as_uint(sc0);
    }
    int b = tid >> 7, d = tid & 127;
    relv[b][d] = rel_embedding[(size_t)sr0[b]*Dd + d];
    if (b == 0) hv[d] = hidden_states[(size_t)shsrc*Dd + d];
    __syncthreads();
    float acc = lin_b[d];
    #pragma unroll 8
    for (int k=0;k<Dd;k++) acc += relv[b][k]*lin_W[(Dd+k)*Dd + d];
    cvv[b][d] = acc; cvec[b*Dd+d] = acc;
    float heur = acc;
    #pragma unroll 8
    for (int k=0;k<Dd;k++) heur += hv[k]*lin_W[k*Dd + d];
    xx[b][d] = heur * hv[d];
    __syncthreads();
    float a2 = m1_b[d];
    #pragma unroll 8
    for (int k=0;k<Dd;k++) a2 += xx[b][k]*m1_W[k*Dd + d];
    pp[b][d] = fmaxf(a2, 0.f) * m2_W[d];
    __syncthreads();
    if (tid < Bq){
      float s = m2_b[0];
      for (int k=0;k<Dd;k++) s += pp[tid][k];
      score[sfh[tid]] = s;
    }
  }
}

// ---------------- k_selz: blocks 0,1 radix-select; blocks 2+ zero accumulators ----------------
__global__ __launch_bounds__(256) void k_selz(
    const float* score, const int* tlist, unsigned* ctr, unsigned long long* thr,
    unsigned* out_deg, float* s1, float* s2, unsigned* mxb, unsigned* mnb, unsigned* cnt){
  int bid = blockIdx.x, tid = threadIdx.x;
  if (bid >= 2){
    int z0 = (bid-2)*256 + tid, zstr = (gridDim.x-2)*256;
    float4 z4 = make_float4(0.f,0.f,0.f,0.f);
    uint4 zi = make_uint4(0u,0u,0u,0u);
    uint4 fi = make_uint4(~0u,~0u,~0u,~0u);
    for (int i=z0; i<MAXACT*Dd/4; i+=zstr){
      ((float4*)s1)[i]=z4; ((float4*)s2)[i]=z4;
      ((uint4*)mxb)[i]=zi; ((uint4*)mnb)[i]=fi;
    }
    for (int i=z0; i<BN; i+=zstr) out_deg[i]=0u;
    for (int i=z0; i<MAXACT; i+=zstr) cnt[i]=0u;
    if (bid==2 && tid<3) ctr[tid]=0u;
    return;
  }
  int b = bid;
  int nt = (int)ctr[3];
  unsigned d0 = ~encf(__uint_as_float(ctr[4]));
  __shared__ unsigned sd[SELCAP];
  __shared__ unsigned short sidx[SELCAP];
  __shared__ unsigned hist[256], histT[256];
  __shared__ int ntb_sh;
  __shared__ unsigned long long pref_sh;
  __shared__ unsigned kk_sh;
  if (tid==0){ ntb_sh = 0; pref_sh = 0ull; kk_sh = K_SEL; }
  __syncthreads();
  int vlo = b*Nn, vhi = vlo + Nn;
  for (int i = tid; i < nt; i += 256){
    int v = tlist[i];
    if (v >= vlo && v < vhi){
      int pos = atomicAdd(&ntb_sh, 1);
      if (pos < SELCAP){
        sd[pos] = ~encf(score[v]);
        sidx[pos] = (unsigned short)(v - vlo);
      }
    }
  }
  __syncthreads();
  int ntb = min(ntb_sh, SELCAP);
  unsigned nvirt = (unsigned)(Nn - ntb);
  for (int pass = 7; pass >= 0; --pass){
    hist[tid] = 0u; histT[tid] = 0u;
    __syncthreads();
    unsigned long long pref = pref_sh;
    int sh_hi = 8*(pass+1);
    for (int j = tid; j < ntb; j += 256){
      unsigned long long key = ((unsigned long long)sd[j] << 32) | (unsigned long long)sidx[j];
      bool ok = (pass==7) || ((key >> sh_hi) == (pref >> sh_hi));
      if (ok) atomicAdd(&hist[(unsigned)(key >> (8*pass)) & 255u], 1u);
      if (pass < 4){
        unsigned idx = sidx[j];
        bool oki = (pass == 3) || ((idx >> sh_hi) == (((unsigned)pref) >> sh_hi));
        if (oki) atomicAdd(&histT[(idx >> (8*pass)) & 255u], 1u);
      }
    }
    __syncthreads();
    if (pass >= 4){
      if (tid == 0){
        unsigned long long keyv_hi = ((unsigned long long)d0 << 32);
        bool ok = (pass==7) || ((keyv_hi >> sh_hi) == (pref >> sh_hi));
        if (ok) atomicAdd(&hist[(d0 >> (8*(pass-4))) & 255u], nvirt);
      }
    } else {
      if ((unsigned)(pref >> 32) == d0){
        unsigned long long hf = 0ull;
        if (pass < 3) hf = (unsigned long long)((((unsigned)pref) >> sh_hi)) << sh_hi;
        unsigned long long lo = hf + ((unsigned long long)tid << (8*pass));
        unsigned long long hi = lo + (1ull << (8*pass));
        unsigned long long nn = (unsigned long long)Nn;
        unsigned long long l2 = lo < nn ? lo : nn;
        unsigned long long h2 = hi < nn ? hi : nn;
        if (h2 > l2){
          unsigned c = (unsigned)(h2 - l2) - histT[tid];
          if (c > 0u) atomicAdd(&hist[tid], c);
        }
      }
    }
    __syncthreads();
    if (tid < 256){
      unsigned kk = kk_sh;
      unsigned cum = 0;
      for (int i=0;i<tid;i++) cum += hist[i];
      unsigned h = hist[tid];
      if (h > 0u && cum < kk && kk <= cum + h){
        pref_sh |= ((unsigned long long)tid) << (8*pass);
        kk_sh = kk - cum;
      }
    }
    __syncthreads();
  }
  if (tid==0) thr[b] = pref_sh;
}

// ---------------- k_degree: out_deg + slot assignment on 0->1 transition ----------------
__global__ void k_degree(const int* ei, const float* score, const unsigned long long* thr,
                         unsigned* out_deg, int* node_slot, int* alist, unsigned* ctr){
  int e = blockIdx.x*blockDim.x + threadIdx.x;
  if (e >= Ee) return;
  unsigned long long th0 = thr[0], th1 = thr[1];
  int s0 = ei[e];
  if (make_key(score[s0], s0) <= th0){
    if (atomicAdd(&out_deg[s0], 1u) == 0u){
      int slot = (int)atomicAdd(&ctr[0], 1u);
      node_slot[s0] = slot; alist[slot] = s0;
    }
  }
  int s1v = s0 + Nn;
  if (make_key(score[s1v], s0) <= th1){
    if (atomicAdd(&out_deg[s1v], 1u) == 0u){
      int slot = (int)atomicAdd(&ctr[0], 1u);
      node_slot[s1v] = slot; alist[slot] = s1v;
    }
  }
}

// ---------------- k_msg: node bookkeeping (k_active fold) + coalesced edge scan + GEMV ----------------
__global__ __launch_bounds__(128) void k_msg(
    const float* hidden, const int* ei, const float* score, const unsigned long long* thr,
    const unsigned* out_deg, const int* node_slot,
    float* slot_deg, unsigned* flag, int* tlist,
    const float* preW, const float* preb,
    float* s1, float* s2, unsigned* mxb, unsigned* mnb, unsigned* cnt, unsigned* ctr){
  int tid = threadIdx.x, bid = blockIdx.x;
  // part A: active-node bookkeeping (out_deg complete from previous dispatch)
  for (int v = bid*128 + tid; v < BN; v += MSG_GRID*128){
    unsigned dg = out_deg[v];
    if (dg > 0u){
      int slot = node_slot[v];
      slot_deg[slot] = (float)dg;
      atomicAdd((float*)&ctr[2], logf((float)dg + 1.0f));
      if (atomicExch(&flag[v], 1u) == 0u){
        int p = (int)atomicAdd(&ctr[3], 1u);
        tlist[p] = v;
      }
    }
  }
  // part B: contiguous edge scan + message GEMV
  __shared__ int qs[256], qd[256], qsl[256];
  __shared__ int qn;
  __shared__ float sdl[4][Dd], ssl[4][Dd];
  __shared__ int dsl[4];
  unsigned long long th0 = thr[0], th1 = thr[1];
  float pb = preb[tid];
  const int CH = (Ee + MSG_GRID - 1)/MSG_GRID;
  int e_beg = bid*CH;
  int e_end = e_beg + CH; if (e_end > Ee) e_end = Ee;
  for (int e0 = e_beg; e0 < e_end; e0 += 128){
    if (tid == 0) qn = 0;
    __syncthreads();
    int e = e0 + tid;
    if (e < e_end){
      int s0 = ei[e], d0 = ei[Ee + e];
      if (make_key(score[s0], s0) <= th0 && out_deg[d0] > 0u){
        int slot = node_slot[d0];
        int p = atomicAdd(&qn, 1);
        qs[p] = s0; qd[p] = d0; qsl[p] = slot;
        atomicAdd(&cnt[slot], 1u);
      }
      int s1v = s0 + Nn, d1v = d0 + Nn;
      if (make_key(score[s1v], s0) <= th1 && out_deg[d1v] > 0u){
        int slot = node_slot[d1v];
        int p = atomicAdd(&qn, 1);
        qs[p] = s1v; qd[p] = d1v; qsl[p] = slot;
        atomicAdd(&cnt[slot], 1u);
      }
    }
    __syncthreads();
    int nq = qn;
    for (int q0 = 0; q0 < nq; q0 += 4){
      int nv = nq - q0; if (nv > 4) nv = 4;
      if (tid < 4) dsl[tid] = qsl[q0 + ((tid < nv) ? tid : 0)];
      #pragma unroll
      for (int e2=0;e2<4;e2++){
        int qq = q0 + ((e2 < nv) ? e2 : 0);
        sdl[e2][tid] = hidden[(size_t)qd[qq]*Dd + tid];
        ssl[e2][tid] = hidden[(size_t)qs[qq]*Dd + tid];
      }
      __syncthreads();
      float a[4] = {pb, pb, pb, pb};
      #pragma unroll 4
      for (int kk=0;kk<Dd;kk++){
        float w0 = preW[kk*Dd + tid];
        float w1 = preW[(Dd+kk)*Dd + tid];
        #pragma unroll
        for (int e2=0;e2<4;e2++) a[e2] += sdl[e2][kk]*w0 + ssl[e2][kk]*w1;
      }
      for (int e2=0;e2<nv;e2++){
        int ds = dsl[e2];
        atomicAdd(&s1[ds*Dd + tid], a[e2]);
        atomicAdd(&s2[ds*Dd + tid], a[e2]*a[e2]);
        atomicMax(&mxb[ds*Dd + tid], encf(a[e2]));
        atomicMin(&mnb[ds*Dd + tid], encf(a[e2]));
      }
      __syncthreads();
    }
  }
}

// ---------------- k_postresid: finalize + post GEMM + out GEMM + residual ----------------
// 64 blocks x 512 threads; per block 32 slots; accumulates all 4 aggregate sections
// in-register (no tpart round-trip), then out-linear + residual.
__global__ __launch_bounds__(512) void k_postresid(
    const unsigned* cnt, const float* s1, const float* s2,
    const unsigned* mxb, const unsigned* mnb, const float* slot_deg,
    const float* postW, const float* postb, const float* outW, const float* outb,
    const int* alist, float* hidden, const unsigned* ctr){
  int na = (int)ctr[0];
  int tile = blockIdx.x;
  if (tile*32 >= na) return;
  __shared__ float lb[32*136];
  __shared__ float wbuf[3*16*128];
  __shared__ float sden[32];
  __shared__ unsigned shas[32];
  int tid = threadIdx.x;
  if (tid < 32){
    unsigned c = cnt[tile*32 + tid];
    sden[tid] = fmaxf((float)c, 1.0f);
    shas[tid] = c;
  }
  __syncthreads();
  int cg = tid & 31, rg = tid >> 5;        // 32 col-groups (x4), 16 row-groups (x2)
  int c0 = cg*4;
  float a0[2][4], a1[2][4], a2[2][4];
  #pragma unroll
  for (int i=0;i<2;i++)
    #pragma unroll
    for (int j=0;j<4;j++){ a0[i][j]=0.f; a1[i][j]=0.f; a2[i][j]=0.f; }
  for (int ch = 0; ch < 4; ++ch){
    for (int idx = tid; idx < 32*Dd; idx += 512){
      int sl = idx >> 7, kk = idx & 127;
      int gi = (tile*32 + sl)*Dd + kk;
      float den = sden[sl];
      float val;
      if (ch == 0)      val = s1[gi]/den;
      else if (ch == 1) val = shas[sl] ? decf(mxb[gi]) : 0.f;
      else if (ch == 2) val = shas[sl] ? decf(mnb[gi]) : 0.f;
      else {
        float mv = s1[gi]/den;
        float var = s2[gi]/den - mv*mv;
        val = sqrtf(fmaxf(var, 0.f) + EPSV);
      }
      lb[sl*136 + kk] = val;
    }
    for (int chunk = 0; chunk < 8; ++chunk){
      __syncthreads();                     // covers lb write (chunk 0) + wbuf reuse
      #pragma unroll
      for (int i = 0; i < 3; ++i){
        int f = tid + i*512;               // 1536 float4
        int q = f >> 9, r = f & 511;
        int kk = r >> 5, c4 = r & 31;
        int grow = q*512 + ch*128 + chunk*16 + kk;
        ((float4*)wbuf)[f] = *(const float4*)(postW + (size_t)grow*Dd + c4*4);
      }
      __syncthreads();
      #pragma unroll
      for (int k4 = 0; k4 < 4; ++k4){
        float4 av0 = *(const float4*)&lb[(rg*2+0)*136 + chunk*16 + k4*4];
        float4 av1 = *(const float4*)&lb[(rg*2+1)*136 + chunk*16 + k4*4];
        #pragma unroll
        for (int j = 0; j < 4; ++j){
          int kk = k4*4 + j;
          float4 w0 = *(const float4*)&wbuf[kk*128 + c0];
          float4 w1 = *(const float4*)&wbuf[(16+kk)*128 + c0];
          float4 w2 = *(const float4*)&wbuf[(32+kk)*128 + c0];
          float av[2] = { (&av0.x)[j], (&av1.x)[j] };
          #pragma unroll
          for (int i=0;i<2;i++){
            float a = av[i];
            a0[i][0] += a*w0.x; a0[i][1] += a*w0.y; a0[i][2] += a*w0.z; a0[i][3] += a*w0.w;
            a1[i][0] += a*w1.x; a1[i][1] += a*w1.y; a1[i][2] += a*w1.z; a1[i][3] += a*w1.w;
            a2[i][0] += a*w2.x; a2[i][1] += a*w2.y; a2[i][2] += a*w2.z; a2[i][3] += a*w2.w;
          }
        }
      }
      __syncthreads();
    }
  }
  // scalers + postb -> tr (reuse lb)
  float logsum = __uint_as_float(ctr[2]);
  float avg = (logsum + (float)(BN - na)*LN2F) / (float)BN;
  #pragma unroll
  for (int i=0;i<2;i++){
    int slot = tile*32 + rg*2 + i;
    float dg = (slot < na) ? slot_deg[slot] : 1.0f;
    float logd = logf(dg + 1.f);
    float al = logd/avg, be = avg/logd;
    float4 pbv = *(const float4*)(postb + c0);
    float4 r;
    r.x = a0[i][0] + al*a1[i][0] + be*a2[i][0] + pbv.x;
    r.y = a0[i][1] + al*a1[i][1] + be*a2[i][1] + pbv.y;
    r.z = a0[i][2] + al*a1[i][2] + be*a2[i][2] + pbv.z;
    r.w = a0[i][3] + al*a1[i][3] + be*a2[i][3] + pbv.w;
    *(float4*)&lb[(rg*2+i)*136 + c0] = r;
  }
  // out-linear + residual
  float4 ob = *(const float4*)(outb + c0);
  float accO[2][4];
  #pragma unroll
  for (int r=0;r<2;r++){ accO[r][0]=ob.x; accO[r][1]=ob.y; accO[r][2]=ob.z; accO[r][3]=ob.w; }
  for (int chunk = 0; chunk < 8; ++chunk){
    __syncthreads();                       // covers tr writes (chunk 0) + wbuf reuse
    {
      int f = tid;                         // 512 float4 exactly
      int kk = f >> 5, c4 = f & 31;
      ((float4*)wbuf)[f] = *(const float4*)(outW + (size_t)(chunk*16 + kk)*Dd + c4*4);
    }
    __syncthreads();
    #pragma unroll
    for (int k4 = 0; k4 < 4; ++k4){
      float4 av[2];
      #pragma unroll
      for (int r=0;r<2;r++)
        av[r] = *(const float4*)&lb[(rg*2+r)*136 + chunk*16 + k4*4];
      #pragma unroll
      for (int j = 0; j < 4; ++j){
        float4 w = *(const float4*)&wbuf[(k4*4+j)*128 + c0];
        #pragma unroll
        for (int r=0;r<2;r++){
          float a = (&av[r].x)[j];
          accO[r][0] += a*w.x; accO[r][1] += a*w.y; accO[r][2] += a*w.z; accO[r][3] += a*w.w;
        }
      }
    }
  }
  #pragma unroll
  for (int r=0;r<2;r++){
    int slot = tile*32 + rg*2 + r;
    if (slot < na){
      int v = alist[slot];
      float* hp = hidden + (size_t)v*Dd + c0;
      float4 h4 = *(float4*)hp;
      h4.x += accO[r][0]; h4.y += accO[r][1]; h4.z += accO[r][2]; h4.w += accO[r][3];
      *(float4*)hp = h4;
    }
  }
}

// ---------------- k_score ----------------
__global__ __launch_bounds__(256) void k_score(
    const float* hidden, const float* cvec, const float* linW,
    const float* m1W, const float* m1b, const float* m2W, const float* m2b,
    const int* tlist, const unsigned* ctr, float* score,
    const int* ovr, int ovr_n, float* outdest){
  int nt = (ovr_n > 0) ? ovr_n : (int)ctr[3];
  const int* list = (ovr_n > 0) ? ovr : tlist;
  int nb = blockIdx.x * 32;
  if (nb >= nt) return;
  __shared__ float sh[32*Dd];
  __shared__ float sx[32*Dd];
  __shared__ float sc[2*Dd];
  __shared__ int   sv[32];
  __shared__ float red[32*33];
  int tid = threadIdx.x;
  if (tid < 32){
    int idx = nb + tid;
    sv[tid] = (idx < nt) ? list[idx] : list[nb];
  }
  sc[tid] = cvec[tid];
  __syncthreads();
  for (int q = tid; q < 32*32; q += 256){
    int row = q >> 5, f4 = q & 31;
    ((float4*)sh)[row*32 + f4] = ((const float4*)(hidden + (size_t)sv[row]*Dd))[f4];
  }
  __syncthreads();
  int cg = tid & 31, rg = tid >> 5;
  int c0 = cg*4;
  float acc[4][4];
  #pragma unroll
  for (int i=0;i<4;i++){ acc[i][0]=0.f; acc[i][1]=0.f; acc[i][2]=0.f; acc[i][3]=0.f; }
  for (int k4=0;k4<32;k4++){
    float4 av[4];
    #pragma unroll
    for (int i=0;i<4;i++) av[i] = ((float4*)sh)[(rg*4+i)*32 + k4];
    #pragma unroll
    for (int j=0;j<4;j++){
      float4 w = *(const float4*)(linW + (size_t)(k4*4+j)*Dd + c0);
      #pragma unroll
      for (int i=0;i<4;i++){
        float a = (&av[i].x)[j];
        acc[i][0] += a*w.x; acc[i][1] += a*w.y; acc[i][2] += a*w.z; acc[i][3] += a*w.w;
      }
    }
  }
  #pragma unroll
  for (int i=0;i<4;i++){
    int row = rg*4 + i;
    int bb = (sv[row] >= Nn) ? 1 : 0;
    float4 cv = *(float4*)&sc[bb*Dd + c0];
    float4 hv = ((float4*)sh)[row*32 + cg];
    float4 x;
    x.x = (acc[i][0] + cv.x)*hv.x;
    x.y = (acc[i][1] + cv.y)*hv.y;
    x.z = (acc[i][2] + cv.z)*hv.z;
    x.w = (acc[i][3] + cv.w)*hv.w;
    ((float4*)sx)[row*32 + cg] = x;
  }
  __syncthreads();
  #pragma unroll
  for (int i=0;i<4;i++){ acc[i][0]=0.f; acc[i][1]=0.f; acc[i][2]=0.f; acc[i][3]=0.f; }
  for (int k4=0;k4<32;k4++){
    float4 av[4];
    #pragma unroll
    for (int i=0;i<4;i++) av[i] = ((float4*)sx)[(rg*4+i)*32 + k4];
    #pragma unroll
    for (int j=0;j<4;j++){
      float4 w = *(const float4*)(m1W + (size_t)(k4*4+j)*Dd + c0);
      #pragma unroll
      for (int i=0;i<4;i++){
        float a = (&av[i].x)[j];
        acc[i][0] += a*w.x; acc[i][1] += a*w.y; acc[i][2] += a*w.z; acc[i][3] += a*w.w;
      }
    }
  }
  float4 mb = *(const float4*)(m1b + c0);
  float4 mw = *(const float4*)(m2W + c0);
  #pragma unroll
  for (int i=0;i<4;i++){
    float p0 = fmaxf(acc[i][0]+mb.x, 0.f)*mw.x;
    float p1 = fmaxf(acc[i][1]+mb.y, 0.f)*mw.y;
    float p2 = fmaxf(acc[i][2]+mb.z, 0.f)*mw.z;
    float p3 = fmaxf(acc[i][3]+mb.w, 0.f)*mw.w;
    red[(rg*4+i)*33 + cg] = p0+p1+p2+p3;
  }
  __syncthreads();
  if (tid < 32){
    float s = m2b[0];
    for (int g=0; g<32; g++) s += red[tid*33 + g];
    if (nb + tid < nt){
      if (outdest) outdest[nb + tid] = s;
      else         score[sv[tid]] = s;
    }
  }
}

// ---------------- launch ----------------
extern "C" void kernel_launch(void* const* d_in, const int* in_sizes, int n_in,
                              void* d_out, int out_size, void* d_ws, size_t ws_size,
                              hipStream_t stream){
  const int*   h_index       = (const int*)d_in[0];
  const int*   r_index       = (const int*)d_in[1];
  const int*   t_index       = (const int*)d_in[2];
  const float* hidden_states = (const float*)d_in[3];
  const int*   edge_index    = (const int*)d_in[4];
  const float* rel_embedding = (const float*)d_in[5];
  const float* lin_W  = (const float*)d_in[6];
  const float* lin_b  = (const float*)d_in[7];
  const float* m1_W   = (const float*)d_in[8];
  const float* m1_b   = (const float*)d_in[9];
  const float* m2_W   = (const float*)d_in[10];
  const float* m2_b   = (const float*)d_in[11];
  const float* pre_W  = (const float*)d_in[12];
  const float* pre_b  = (const float*)d_in[13];
  const float* post_W = (const float*)d_in[14];
  const float* post_b = (const float*)d_in[15];
  const float* out_W  = (const float*)d_in[16];
  const float* out_b  = (const float*)d_in[17];

  char* ws = (char*)d_ws;
  float*    hidden   = (float*)(ws + HID_OFF);
  float*    score    = (float*)(ws + SCORE_OFF);
  float*    cvec     = (float*)(ws + CVEC_OFF);
  int*      hdr      = (int*)(ws + HDR_OFF);
  unsigned long long* thr = (unsigned long long*)(ws + THR_OFF);
  unsigned* out_deg  = (unsigned*)(ws + DEG_OFF);
  int*      node_slot= (int*)(ws + SLOT_OFF);
  unsigned* cnt      = (unsigned*)(ws + CNT_OFF);
  float*    slot_deg = (float*)(ws + SDEG_OFF);
  float*    s1       = (float*)(ws + S1_OFF);
  float*    s2       = (float*)(ws + S2_OFF);
  unsigned* mxb      = (unsigned*)(ws + MXB_OFF);
  unsigned* mnb      = (unsigned*)(ws + MNB_OFF);
  int*      alist    = (int*)(ws + ALIST_OFF);
  unsigned* flag     = (unsigned*)(ws + FLAG_OFF);
  int*      tlist    = (int*)(ws + TLIST_OFF);
  unsigned* ctr      = (unsigned*)(ws + CTR_OFF);

  k_init<<<2048, 256, 0, stream>>>(h_index, r_index, t_index, hidden_states, rel_embedding,
                                   lin_W, lin_b, m1_W, m1_b, m2_W, m2_b,
                                   hdr, cvec, hidden, score, flag, tlist, ctr);
  for (int l = 0; l < Ll; ++l){
    const float* preWl  = pre_W  + (size_t)l*2*Dd*Dd;
    const float* prebl  = pre_b  + (size_t)l*Dd;
    const float* postWl = post_W + (size_t)l*12*Dd*Dd;
    const float* postbl = post_b + (size_t)l*Dd;
    const float* outWl  = out_W  + (size_t)l*Dd*Dd;
    const float* outbl  = out_b  + (size_t)l*Dd;

    k_selz<<<512, 256, 0, stream>>>(score, tlist, ctr, thr, out_deg, s1, s2, mxb, mnb, cnt);
    k_degree<<<(Ee + 255)/256, 256, 0, stream>>>(edge_index, score, thr,
                                                 out_deg, node_slot, alist, ctr);
    k_msg<<<MSG_GRID, 128, 0, stream>>>(hidden, edge_index, score, thr, out_deg, node_slot,
                                        slot_deg, flag, tlist, preWl, prebl,
                                        s1, s2, mxb, mnb, cnt, ctr);
    k_postresid<<<MAXACT/32, 512, 0, stream>>>(cnt, s1, s2, mxb, mnb, slot_deg,
                                               postWl, postbl, outWl, outbl,
                                               alist, hidden, ctr);
    if (l < Ll-1){
      k_score<<<MAXTOUCH/32, 256, 0, stream>>>(hidden, cvec, lin_W, m1_W, m1_b, m2_W, m2_b,
                                               tlist, ctr, score, tlist, 0, nullptr);
    } else {
      k_score<<<1, 256, 0, stream>>>(hidden, cvec, lin_W, m1_W, m1_b, m2_W, m2_b,
                                     tlist, ctr, score, hdr + 4, Bq*NEG, (float*)d_out);
    }
  }
}

// Round 9
// 489.791 us; speedup vs baseline: 1.8145x; 1.8145x over previous
//
#include <hip/hip_runtime.h>
#include <math.h>

#define Bq 2
#define NEG 16
#define Nn 10000
#define Ee 80000
#define Dd 128
#define NUM_REL 237
#define Ll 3
#define K_SEL 1000
#define BN (Bq*Nn)
#define EPSV 1e-5f
#define MAXACT 2048
#define MAXTOUCH 8192
#define SELCAP 3328
#define LN2F 0.69314718056f
#define MSG_GRID 512

// ---------------- workspace layout (bytes) ----------------
constexpr size_t HID_OFF   = 0;                                   // BN*D f32
constexpr size_t SCORE_OFF = HID_OFF   + (size_t)BN*Dd*4;         // BN f32
constexpr size_t CVEC_OFF  = SCORE_OFF + (size_t)BN*4;            // B*D f32
constexpr size_t HDR_OFF   = CVEC_OFF  + (size_t)Bq*Dd*4;         // 64 i32
constexpr size_t THR_OFF   = HDR_OFF   + 64*4;                    // B u64
constexpr size_t DEG_OFF   = THR_OFF   + 64*8;                    // BN u32
constexpr size_t SLOT_OFF  = DEG_OFF   + (size_t)BN*4;            // BN i32
constexpr size_t CNT_OFF   = SLOT_OFF  + (size_t)BN*4;            // MAXACT u32
constexpr size_t SDEG_OFF  = CNT_OFF   + (size_t)MAXACT*4;        // MAXACT f32
constexpr size_t S1_OFF    = SDEG_OFF  + (size_t)MAXACT*4;        // MAXACT*D f32
constexpr size_t S2_OFF    = S1_OFF    + (size_t)MAXACT*Dd*4;
constexpr size_t MXB_OFF   = S2_OFF    + (size_t)MAXACT*Dd*4;     // MAXACT*D u32
constexpr size_t MNB_OFF   = MXB_OFF   + (size_t)MAXACT*Dd*4;
constexpr size_t TPART_OFF = MNB_OFF   + (size_t)MAXACT*Dd*4;     // 4*MAXACT*D f32
constexpr size_t ALIST_OFF = TPART_OFF + (size_t)4*MAXACT*Dd*4;   // MAXACT i32
constexpr size_t FLAG_OFF  = ALIST_OFF + (size_t)MAXACT*4;        // BN u32
constexpr size_t TLIST_OFF = FLAG_OFF  + (size_t)BN*4;            // MAXTOUCH i32
constexpr size_t CTR_OFF   = TLIST_OFF + (size_t)MAXTOUCH*4;      // 16 u32
// ctr[0]=na ctr[2]=log-sum f32bits ctr[3]=ntouched ctr[4]=sc0 bits

// ---------------- helpers ----------------
__device__ __forceinline__ unsigned encf(float f){
  unsigned u = __float_as_uint(f);
  return (u & 0x80000000u) ? ~u : (u | 0x80000000u);
}
__device__ __forceinline__ float decf(unsigned e){
  unsigned u = (e & 0x80000000u) ? (e & 0x7FFFFFFFu) : ~e;
  return __uint_as_float(u);
}
__device__ __forceinline__ unsigned long long make_key(float f, int i){
  unsigned d = ~encf(f);
  return ((unsigned long long)d << 32) | (unsigned)i;
}

// ---------------- k_init: zero+fill+boundary+prep ----------------
__global__ __launch_bounds__(256) void k_init(
    const int* h_index, const int* r_index, const int* t_index,
    const float* hidden_states, const float* rel_embedding,
    const float* lin_W, const float* lin_b, const float* m1_W, const float* m1_b,
    const float* m2_W, const float* m2_b,
    int* hdr, float* cvec, float* hidden, float* score,
    unsigned* flag, int* tlist, unsigned* ctr){
  __shared__ int sfh[Bq], sft[Bq], sr0[Bq], shsrc, stsrc;
  __shared__ float sp[Dd];
  __shared__ float ssc0;
  __shared__ float relv[Bq][Dd], cvv[Bq][Dd], hv[Dd], xx[Bq][Dd], pp[Bq][Dd];
  int tid = threadIdx.x;
  if (tid == 0){
    for (int b=0;b<Bq;b++){
      bool eq = true;
      for (int j=1;j<NEG;j++) eq = eq && (h_index[b*NEG+j]==h_index[b*NEG]);
      int h0 = eq ? h_index[b*NEG] : t_index[b*NEG];
      int t0 = eq ? t_index[b*NEG] : h_index[b*NEG];
      int r0 = eq ? r_index[b*NEG] : r_index[b*NEG] + NUM_REL;
      sfh[b] = h0 + b*Nn; sft[b] = t0 + b*Nn; sr0[b] = r0;
      if (b==0){ shsrc = h0; stsrc = t0; }
    }
  }
  if (tid < Dd) sp[tid] = fmaxf(m1_b[tid], 0.f) * m2_W[tid];
  __syncthreads();
  if (tid == 0){
    float s = m2_b[0];
    for (int k=0;k<Dd;k++) s += sp[k];
    ssc0 = s;
  }
  __syncthreads();
  float sc0 = ssc0;
  int fh0 = sfh[0], fh1 = sfh[1], ft0 = sft[0], ft1 = sft[1];
  int gth = blockIdx.x*256 + tid, gstr = gridDim.x*256;
  for (int i = gth; i < BN*Dd/4; i += gstr){
    int row = i >> 5, c4 = i & 31;
    float4 v;
    if (row == fh0 || row == fh1)
      v = ((const float4*)(hidden_states + (size_t)shsrc*Dd))[c4];
    else if (row == ft0 || row == ft1)
      v = ((const float4*)(hidden_states + (size_t)stsrc*Dd))[c4];
    else v = make_float4(0.f,0.f,0.f,0.f);
    ((float4*)hidden)[i] = v;
  }
  for (int i = gth; i < BN; i += gstr){
    flag[i] = (i==fh0 || i==fh1 || i==ft0 || i==ft1) ? 1u : 0u;
    if (i != fh0 && i != fh1) score[i] = sc0;
  }
  if (blockIdx.x == 0){
    if (tid == 0){
      int tl[4]; int n = 0;
      for (int b=0;b<Bq;b++){
        hdr[b] = sfh[b]; hdr[2+b] = sft[b];
        bool eq = true;
        for (int j=1;j<NEG;j++) eq = eq && (h_index[b*NEG+j]==h_index[b*NEG]);
        for (int j=0;j<NEG;j++){
          int tj = eq ? t_index[b*NEG+j] : h_index[b*NEG+j];
          hdr[4 + b*NEG + j] = tj + b*Nn;
        }
        int c1 = sft[b]; bool f1=false;
        for (int q=0;q<n;q++) f1 = f1 || (tl[q]==c1);
        if (!f1) tl[n++] = c1;
        int c2 = sfh[b]; bool f2=false;
        for (int q=0;q<n;q++) f2 = f2 || (tl[q]==c2);
        if (!f2) tl[n++] = c2;
      }
      for (int q=0;q<n;q++) tlist[q] = tl[q];
      ctr[3] = (unsigned)n;
      ctr[4] = __float_as_uint(sc0);
    }
    int b = tid >> 7, d = tid & 127;
    relv[b][d] = rel_embedding[(size_t)sr0[b]*Dd + d];
    if (b == 0) hv[d] = hidden_states[(size_t)shsrc*Dd + d];
    __syncthreads();
    float acc = lin_b[d];
    #pragma unroll 8
    for (int k=0;k<Dd;k++) acc += relv[b][k]*lin_W[(Dd+k)*Dd + d];
    cvv[b][d] = acc; cvec[b*Dd+d] = acc;
    float heur = acc;
    #pragma unroll 8
    for (int k=0;k<Dd;k++) heur += hv[k]*lin_W[k*Dd + d];
    xx[b][d] = heur * hv[d];
    __syncthreads();
    float a2 = m1_b[d];
    #pragma unroll 8
    for (int k=0;k<Dd;k++) a2 += xx[b][k]*m1_W[k*Dd + d];
    pp[b][d] = fmaxf(a2, 0.f) * m2_W[d];
    __syncthreads();
    if (tid < Bq){
      float s = m2_b[0];
      for (int k=0;k<Dd;k++) s += pp[tid][k];
      score[sfh[tid]] = s;
    }
  }
}

// ---------------- k_selz: blocks 0,1 radix-select; blocks 2+ zero accumulators ----------------
__global__ __launch_bounds__(256) void k_selz(
    const float* score, const int* tlist, unsigned* ctr, unsigned long long* thr,
    unsigned* out_deg, float* s1, float* s2, unsigned* mxb, unsigned* mnb, unsigned* cnt){
  int bid = blockIdx.x, tid = threadIdx.x;
  if (bid >= 2){
    int z0 = (bid-2)*256 + tid, zstr = (gridDim.x-2)*256;
    float4 z4 = make_float4(0.f,0.f,0.f,0.f);
    uint4 zi = make_uint4(0u,0u,0u,0u);
    uint4 fi = make_uint4(~0u,~0u,~0u,~0u);
    for (int i=z0; i<MAXACT*Dd/4; i+=zstr){
      ((float4*)s1)[i]=z4; ((float4*)s2)[i]=z4;
      ((uint4*)mxb)[i]=zi; ((uint4*)mnb)[i]=fi;
    }
    for (int i=z0; i<BN; i+=zstr) out_deg[i]=0u;
    for (int i=z0; i<MAXACT; i+=zstr) cnt[i]=0u;
    if (bid==2 && tid<3) ctr[tid]=0u;
    return;
  }
  int b = bid;
  int nt = (int)ctr[3];
  unsigned d0 = ~encf(__uint_as_float(ctr[4]));
  __shared__ unsigned sd[SELCAP];
  __shared__ unsigned short sidx[SELCAP];
  __shared__ unsigned hist[256], histT[256];
  __shared__ int ntb_sh;
  __shared__ unsigned long long pref_sh;
  __shared__ unsigned kk_sh;
  if (tid==0){ ntb_sh = 0; pref_sh = 0ull; kk_sh = K_SEL; }
  __syncthreads();
  int vlo = b*Nn, vhi = vlo + Nn;
  for (int i = tid; i < nt; i += 256){
    int v = tlist[i];
    if (v >= vlo && v < vhi){
      int pos = atomicAdd(&ntb_sh, 1);
      if (pos < SELCAP){
        sd[pos] = ~encf(score[v]);
        sidx[pos] = (unsigned short)(v - vlo);
      }
    }
  }
  __syncthreads();
  int ntb = min(ntb_sh, SELCAP);
  unsigned nvirt = (unsigned)(Nn - ntb);
  for (int pass = 7; pass >= 0; --pass){
    hist[tid] = 0u; histT[tid] = 0u;
    __syncthreads();
    unsigned long long pref = pref_sh;
    int sh_hi = 8*(pass+1);
    for (int j = tid; j < ntb; j += 256){
      unsigned long long key = ((unsigned long long)sd[j] << 32) | (unsigned long long)sidx[j];
      bool ok = (pass==7) || ((key >> sh_hi) == (pref >> sh_hi));
      if (ok) atomicAdd(&hist[(unsigned)(key >> (8*pass)) & 255u], 1u);
      if (pass < 4){
        unsigned idx = sidx[j];
        bool oki = (pass == 3) || ((idx >> sh_hi) == (((unsigned)pref) >> sh_hi));
        if (oki) atomicAdd(&histT[(idx >> (8*pass)) & 255u], 1u);
      }
    }
    __syncthreads();
    if (pass >= 4){
      if (tid == 0){
        unsigned long long keyv_hi = ((unsigned long long)d0 << 32);
        bool ok = (pass==7) || ((keyv_hi >> sh_hi) == (pref >> sh_hi));
        if (ok) atomicAdd(&hist[(d0 >> (8*(pass-4))) & 255u], nvirt);
      }
    } else {
      if ((unsigned)(pref >> 32) == d0){
        unsigned long long hf = 0ull;
        if (pass < 3) hf = (unsigned long long)((((unsigned)pref) >> sh_hi)) << sh_hi;
        unsigned long long lo = hf + ((unsigned long long)tid << (8*pass));
        unsigned long long hi = lo + (1ull << (8*pass));
        unsigned long long nn = (unsigned long long)Nn;
        unsigned long long l2 = lo < nn ? lo : nn;
        unsigned long long h2 = hi < nn ? hi : nn;
        if (h2 > l2){
          unsigned c = (unsigned)(h2 - l2) - histT[tid];
          if (c > 0u) atomicAdd(&hist[tid], c);
        }
      }
    }
    __syncthreads();
    if (tid < 256){
      unsigned kk = kk_sh;
      unsigned cum = 0;
      for (int i=0;i<tid;i++) cum += hist[i];
      unsigned h = hist[tid];
      if (h > 0u && cum < kk && kk <= cum + h){
        pref_sh |= ((unsigned long long)tid) << (8*pass);
        kk_sh = kk - cum;
      }
    }
    __syncthreads();
  }
  if (tid==0) thr[b] = pref_sh;
}

// ---------------- k_degree: out_deg + slot assignment on 0->1 transition ----------------
__global__ void k_degree(const int* ei, const float* score, const unsigned long long* thr,
                         unsigned* out_deg, int* node_slot, int* alist, unsigned* ctr){
  int e = blockIdx.x*blockDim.x + threadIdx.x;
  if (e >= Ee) return;
  unsigned long long th0 = thr[0], th1 = thr[1];
  int s0 = ei[e];
  if (make_key(score[s0], s0) <= th0){
    if (atomicAdd(&out_deg[s0], 1u) == 0u){
      int slot = (int)atomicAdd(&ctr[0], 1u);
      node_slot[s0] = slot; alist[slot] = s0;
    }
  }
  int s1v = s0 + Nn;
  if (make_key(score[s1v], s0) <= th1){
    if (atomicAdd(&out_deg[s1v], 1u) == 0u){
      int slot = (int)atomicAdd(&ctr[0], 1u);
      node_slot[s1v] = slot; alist[slot] = s1v;
    }
  }
}

// ---------------- k_msg: node bookkeeping + coalesced edge scan + message GEMV ----------------
__global__ __launch_bounds__(128) void k_msg(
    const float* hidden, const int* ei, const float* score, const unsigned long long* thr,
    const unsigned* out_deg, const int* node_slot,
    float* slot_deg, unsigned* flag, int* tlist,
    const float* preW, const float* preb,
    float* s1, float* s2, unsigned* mxb, unsigned* mnb, unsigned* cnt, unsigned* ctr){
  int tid = threadIdx.x, bid = blockIdx.x;
  for (int v = bid*128 + tid; v < BN; v += MSG_GRID*128){
    unsigned dg = out_deg[v];
    if (dg > 0u){
      int slot = node_slot[v];
      slot_deg[slot] = (float)dg;
      atomicAdd((float*)&ctr[2], logf((float)dg + 1.0f));
      if (atomicExch(&flag[v], 1u) == 0u){
        int p = (int)atomicAdd(&ctr[3], 1u);
        tlist[p] = v;
      }
    }
  }
  __shared__ int qs[256], qd[256], qsl[256];
  __shared__ int qn;
  __shared__ float sdl[4][Dd], ssl[4][Dd];
  __shared__ int dsl[4];
  unsigned long long th0 = thr[0], th1 = thr[1];
  float pb = preb[tid];
  const int CH = (Ee + MSG_GRID - 1)/MSG_GRID;
  int e_beg = bid*CH;
  int e_end = e_beg + CH; if (e_end > Ee) e_end = Ee;
  for (int e0 = e_beg; e0 < e_end; e0 += 128){
    if (tid == 0) qn = 0;
    __syncthreads();
    int e = e0 + tid;
    if (e < e_end){
      int s0 = ei[e], d0 = ei[Ee + e];
      if (make_key(score[s0], s0) <= th0 && out_deg[d0] > 0u){
        int slot = node_slot[d0];
        int p = atomicAdd(&qn, 1);
        qs[p] = s0; qd[p] = d0; qsl[p] = slot;
        atomicAdd(&cnt[slot], 1u);
      }
      int s1v = s0 + Nn, d1v = d0 + Nn;
      if (make_key(score[s1v], s0) <= th1 && out_deg[d1v] > 0u){
        int slot = node_slot[d1v];
        int p = atomicAdd(&qn, 1);
        qs[p] = s1v; qd[p] = d1v; qsl[p] = slot;
        atomicAdd(&cnt[slot], 1u);
      }
    }
    __syncthreads();
    int nq = qn;
    for (int q0 = 0; q0 < nq; q0 += 4){
      int nv = nq - q0; if (nv > 4) nv = 4;
      if (tid < 4) dsl[tid] = qsl[q0 + ((tid < nv) ? tid : 0)];
      #pragma unroll
      for (int e2=0;e2<4;e2++){
        int qq = q0 + ((e2 < nv) ? e2 : 0);
        sdl[e2][tid] = hidden[(size_t)qd[qq]*Dd + tid];
        ssl[e2][tid] = hidden[(size_t)qs[qq]*Dd + tid];
      }
      __syncthreads();
      float a[4] = {pb, pb, pb, pb};
      #pragma unroll 4
      for (int kk=0;kk<Dd;kk++){
        float w0 = preW[kk*Dd + tid];
        float w1 = preW[(Dd+kk)*Dd + tid];
        #pragma unroll
        for (int e2=0;e2<4;e2++) a[e2] += sdl[e2][kk]*w0 + ssl[e2][kk]*w1;
      }
      for (int e2=0;e2<nv;e2++){
        int ds = dsl[e2];
        atomicAdd(&s1[ds*Dd + tid], a[e2]);
        atomicAdd(&s2[ds*Dd + tid], a[e2]*a[e2]);
        atomicMax(&mxb[ds*Dd + tid], encf(a[e2]));
        atomicMin(&mnb[ds*Dd + tid], encf(a[e2]));
      }
      __syncthreads();
    }
  }
}

// ---------------- k_post (R4-proven: 256 blocks = 64 tiles x 4 agg-chunks) ----------------
__global__ __launch_bounds__(512) void k_post(
    const unsigned* cnt, const float* s1, const float* s2,
    const unsigned* mxb, const unsigned* mnb, const float* slot_deg,
    const float* postW, float* tpart, const unsigned* ctr){
  int na = (int)ctr[0];
  int bid = blockIdx.x;
  int tile = bid & 63, ch = bid >> 6;
  if (tile*32 >= na) return;
  float logsum = __uint_as_float(ctr[2]);
  float avg = (logsum + (float)(BN - na)*LN2F) / (float)BN;
  __shared__ float lb[32*136];
  __shared__ float wbuf[3*16*128];
  __shared__ float sden[32];
  __shared__ unsigned shas[32];
  int tid = threadIdx.x;
  if (tid < 32){
    unsigned c = cnt[tile*32 + tid];
    sden[tid] = fmaxf((float)c, 1.0f);
    shas[tid] = c;
  }
  __syncthreads();
  for (int idx = tid; idx < 32*Dd; idx += 512){
    int sl = idx >> 7, kk = idx & 127;
    int gi = (tile*32 + sl)*Dd + kk;
    float den = sden[sl];
    float val;
    if (ch == 0)      val = s1[gi]/den;
    else if (ch == 1) val = shas[sl] ? decf(mxb[gi]) : 0.f;
    else if (ch == 2) val = shas[sl] ? decf(mnb[gi]) : 0.f;
    else {
      float mv = s1[gi]/den;
      float var = s2[gi]/den - mv*mv;
      val = sqrtf(fmaxf(var, 0.f) + EPSV);
    }
    lb[sl*136 + kk] = val;
  }
  int cg = tid & 31, rg = tid >> 5;
  int c0 = cg*4;
  float a0[2][4], a1[2][4], a2[2][4];
  #pragma unroll
  for (int i=0;i<2;i++)
    #pragma unroll
    for (int j=0;j<4;j++){ a0[i][j]=0.f; a1[i][j]=0.f; a2[i][j]=0.f; }
  for (int chunk = 0; chunk < 8; ++chunk){
    __syncthreads();
    #pragma unroll
    for (int i = 0; i < 3; ++i){
      int f = tid + i*512;
      int q = f >> 9, r = f & 511;
      int kk = r >> 5, c4 = r & 31;
      int grow = q*512 + ch*128 + chunk*16 + kk;
      ((float4*)wbuf)[f] = *(const float4*)(postW + (size_t)grow*Dd + c4*4);
    }
    __syncthreads();
    #pragma unroll
    for (int k4 = 0; k4 < 4; ++k4){
      float4 av0 = *(const float4*)&lb[(rg*2+0)*136 + chunk*16 + k4*4];
      float4 av1 = *(const float4*)&lb[(rg*2+1)*136 + chunk*16 + k4*4];
      #pragma unroll
      for (int j = 0; j < 4; ++j){
        int kk = k4*4 + j;
        float4 w0 = *(const float4*)&wbuf[kk*128 + c0];
        float4 w1 = *(const float4*)&wbuf[(16+kk)*128 + c0];
        float4 w2 = *(const float4*)&wbuf[(32+kk)*128 + c0];
        float av[2] = { (&av0.x)[j], (&av1.x)[j] };
        #pragma unroll
        for (int i=0;i<2;i++){
          float a = av[i];
          a0[i][0] += a*w0.x; a0[i][1] += a*w0.y; a0[i][2] += a*w0.z; a0[i][3] += a*w0.w;
          a1[i][0] += a*w1.x; a1[i][1] += a*w1.y; a1[i][2] += a*w1.z; a1[i][3] += a*w1.w;
          a2[i][0] += a*w2.x; a2[i][1] += a*w2.y; a2[i][2] += a*w2.z; a2[i][3] += a*w2.w;
        }
      }
    }
  }
  #pragma unroll
  for (int i=0;i<2;i++){
    int slot = tile*32 + rg*2 + i;
    if (slot < na){
      float dg = slot_deg[slot];
      float logd = logf(dg + 1.f);
      float al = logd/avg, be = avg/logd;
      float4 r;
      r.x = a0[i][0] + al*a1[i][0] + be*a2[i][0];
      r.y = a0[i][1] + al*a1[i][1] + be*a2[i][1];
      r.z = a0[i][2] + al*a1[i][2] + be*a2[i][2];
      r.w = a0[i][3] + al*a1[i][3] + be*a2[i][3];
      *(float4*)(tpart + (size_t)ch*MAXACT*Dd + (size_t)slot*Dd + c0) = r;
    }
  }
}

// ---------------- k_out_resid (R4-proven) ----------------
__global__ __launch_bounds__(256) void k_out_resid(
    const float* tpart, const int* alist, const float* outW, const float* outb,
    const float* postb, float* hidden, const unsigned* ctr){
  int na = (int)ctr[0];
  int tile = blockIdx.x;
  if (tile*32 >= na) return;
  __shared__ float tr[32*136];
  __shared__ float wbuf[16*128];
  int tid = threadIdx.x;
  for (int idx = tid; idx < 32*Dd; idx += 256){
    int sl = idx >> 7, kk = idx & 127;
    size_t o = (size_t)(tile*32 + sl)*Dd + kk;
    tr[sl*136 + kk] = tpart[o] + tpart[(size_t)MAXACT*Dd + o]
                    + tpart[(size_t)2*MAXACT*Dd + o] + tpart[(size_t)3*MAXACT*Dd + o]
                    + postb[kk];
  }
  int cg = tid & 31, rg = tid >> 5;
  int c0 = cg*4;
  float4 ob = *(const float4*)(outb + c0);
  float acc[4][4];
  #pragma unroll
  for (int r=0;r<4;r++){ acc[r][0]=ob.x; acc[r][1]=ob.y; acc[r][2]=ob.z; acc[r][3]=ob.w; }
  for (int chunk = 0; chunk < 8; ++chunk){
    __syncthreads();
    #pragma unroll
    for (int i = 0; i < 2; ++i){
      int f = tid + i*256;
      int kk = f >> 5, c4 = f & 31;
      ((float4*)wbuf)[f] = *(const float4*)(outW + (size_t)(chunk*16 + kk)*Dd + c4*4);
    }
    __syncthreads();
    #pragma unroll
    for (int k4 = 0; k4 < 4; ++k4){
      float4 av[4];
      #pragma unroll
      for (int r=0;r<4;r++)
        av[r] = *(const float4*)&tr[(rg*4+r)*136 + chunk*16 + k4*4];
      #pragma unroll
      for (int j = 0; j < 4; ++j){
        float4 w = *(const float4*)&wbuf[(k4*4+j)*128 + c0];
        #pragma unroll
        for (int r=0;r<4;r++){
          float a = (&av[r].x)[j];
          acc[r][0] += a*w.x; acc[r][1] += a*w.y; acc[r][2] += a*w.z; acc[r][3] += a*w.w;
        }
      }
    }
  }
  #pragma unroll
  for (int r=0;r<4;r++){
    int slot = tile*32 + rg*4 + r;
    if (slot < na){
      int v = alist[slot];
      float* hp = hidden + (size_t)v*Dd + c0;
      float4 h4 = *(float4*)hp;
      h4.x += acc[r][0]; h4.y += acc[r][1]; h4.z += acc[r][2]; h4.w += acc[r][3];
      *(float4*)hp = h4;
    }
  }
}

// ---------------- k_score ----------------
__global__ __launch_bounds__(256) void k_score(
    const float* hidden, const float* cvec, const float* linW,
    const float* m1W, const float* m1b, const float* m2W, const float* m2b,
    const int* tlist, const unsigned* ctr, float* score,
    const int* ovr, int ovr_n, float* outdest){
  int nt = (ovr_n > 0) ? ovr_n : (int)ctr[3];
  const int* list = (ovr_n > 0) ? ovr : tlist;
  int nb = blockIdx.x * 32;
  if (nb >= nt) return;
  __shared__ float sh[32*Dd];
  __shared__ float sx[32*Dd];
  __shared__ float sc[2*Dd];
  __shared__ int   sv[32];
  __shared__ float red[32*33];
  int tid = threadIdx.x;
  if (tid < 32){
    int idx = nb + tid;
    sv[tid] = (idx < nt) ? list[idx] : list[nb];
  }
  sc[tid] = cvec[tid];
  __syncthreads();
  for (int q = tid; q < 32*32; q += 256){
    int row = q >> 5, f4 = q & 31;
    ((float4*)sh)[row*32 + f4] = ((const float4*)(hidden + (size_t)sv[row]*Dd))[f4];
  }
  __syncthreads();
  int cg = tid & 31, rg = tid >> 5;
  int c0 = cg*4;
  float acc[4][4];
  #pragma unroll
  for (int i=0;i<4;i++){ acc[i][0]=0.f; acc[i][1]=0.f; acc[i][2]=0.f; acc[i][3]=0.f; }
  for (int k4=0;k4<32;k4++){
    float4 av[4];
    #pragma unroll
    for (int i=0;i<4;i++) av[i] = ((float4*)sh)[(rg*4+i)*32 + k4];
    #pragma unroll
    for (int j=0;j<4;j++){
      float4 w = *(const float4*)(linW + (size_t)(k4*4+j)*Dd + c0);
      #pragma unroll
      for (int i=0;i<4;i++){
        float a = (&av[i].x)[j];
        acc[i][0] += a*w.x; acc[i][1] += a*w.y; acc[i][2] += a*w.z; acc[i][3] += a*w.w;
      }
    }
  }
  #pragma unroll
  for (int i=0;i<4;i++){
    int row = rg*4 + i;
    int bb = (sv[row] >= Nn) ? 1 : 0;
    float4 cv = *(float4*)&sc[bb*Dd + c0];
    float4 hv = ((float4*)sh)[row*32 + cg];
    float4 x;
    x.x = (acc[i][0] + cv.x)*hv.x;
    x.y = (acc[i][1] + cv.y)*hv.y;
    x.z = (acc[i][2] + cv.z)*hv.z;
    x.w = (acc[i][3] + cv.w)*hv.w;
    ((float4*)sx)[row*32 + cg] = x;
  }
  __syncthreads();
  #pragma unroll
  for (int i=0;i<4;i++){ acc[i][0]=0.f; acc[i][1]=0.f; acc[i][2]=0.f; acc[i][3]=0.f; }
  for (int k4=0;k4<32;k4++){
    float4 av[4];
    #pragma unroll
    for (int i=0;i<4;i++) av[i] = ((float4*)sx)[(rg*4+i)*32 + k4];
    #pragma unroll
    for (int j=0;j<4;j++){
      float4 w = *(const float4*)(m1W + (size_t)(k4*4+j)*Dd + c0);
      #pragma unroll
      for (int i=0;i<4;i++){
        float a = (&av[i].x)[j];
        acc[i][0] += a*w.x; acc[i][1] += a*w.y; acc[i][2] += a*w.z; acc[i][3] += a*w.w;
      }
    }
  }
  float4 mb = *(const float4*)(m1b + c0);
  float4 mw = *(const float4*)(m2W + c0);
  #pragma unroll
  for (int i=0;i<4;i++){
    float p0 = fmaxf(acc[i][0]+mb.x, 0.f)*mw.x;
    float p1 = fmaxf(acc[i][1]+mb.y, 0.f)*mw.y;
    float p2 = fmaxf(acc[i][2]+mb.z, 0.f)*mw.z;
    float p3 = fmaxf(acc[i][3]+mb.w, 0.f)*mw.w;
    red[(rg*4+i)*33 + cg] = p0+p1+p2+p3;
  }
  __syncthreads();
  if (tid < 32){
    float s = m2b[0];
    for (int g=0; g<32; g++) s += red[tid*33 + g];
    if (nb + tid < nt){
      if (outdest) outdest[nb + tid] = s;
      else         score[sv[tid]] = s;
    }
  }
}

// ---------------- launch ----------------
extern "C" void kernel_launch(void* const* d_in, const int* in_sizes, int n_in,
                              void* d_out, int out_size, void* d_ws, size_t ws_size,
                              hipStream_t stream){
  const int*   h_index       = (const int*)d_in[0];
  const int*   r_index       = (const int*)d_in[1];
  const int*   t_index       = (const int*)d_in[2];
  const float* hidden_states = (const float*)d_in[3];
  const int*   edge_index    = (const int*)d_in[4];
  const float* rel_embedding = (const float*)d_in[5];
  const float* lin_W  = (const float*)d_in[6];
  const float* lin_b  = (const float*)d_in[7];
  const float* m1_W   = (const float*)d_in[8];
  const float* m1_b   = (const float*)d_in[9];
  const float* m2_W   = (const float*)d_in[10];
  const float* m2_b   = (const float*)d_in[11];
  const float* pre_W  = (const float*)d_in[12];
  const float* pre_b  = (const float*)d_in[13];
  const float* post_W = (const float*)d_in[14];
  const float* post_b = (const float*)d_in[15];
  const float* out_W  = (const float*)d_in[16];
  const float* out_b  = (const float*)d_in[17];

  char* ws = (char*)d_ws;
  float*    hidden   = (float*)(ws + HID_OFF);
  float*    score    = (float*)(ws + SCORE_OFF);
  float*    cvec     = (float*)(ws + CVEC_OFF);
  int*      hdr      = (int*)(ws + HDR_OFF);
  unsigned long long* thr = (unsigned long long*)(ws + THR_OFF);
  unsigned* out_deg  = (unsigned*)(ws + DEG_OFF);
  int*      node_slot= (int*)(ws + SLOT_OFF);
  unsigned* cnt      = (unsigned*)(ws + CNT_OFF);
  float*    slot_deg = (float*)(ws + SDEG_OFF);
  float*    s1       = (float*)(ws + S1_OFF);
  float*    s2       = (float*)(ws + S2_OFF);
  unsigned* mxb      = (unsigned*)(ws + MXB_OFF);
  unsigned* mnb      = (unsigned*)(ws + MNB_OFF);
  float*    tpart    = (float*)(ws + TPART_OFF);
  int*      alist    = (int*)(ws + ALIST_OFF);
  unsigned* flag     = (unsigned*)(ws + FLAG_OFF);
  int*      tlist    = (int*)(ws + TLIST_OFF);
  unsigned* ctr      = (unsigned*)(ws + CTR_OFF);

  k_init<<<2048, 256, 0, stream>>>(h_index, r_index, t_index, hidden_states, rel_embedding,
                                   lin_W, lin_b, m1_W, m1_b, m2_W, m2_b,
                                   hdr, cvec, hidden, score, flag, tlist, ctr);
  for (int l = 0; l < Ll; ++l){
    const float* preWl  = pre_W  + (size_t)l*2*Dd*Dd;
    const float* prebl  = pre_b  + (size_t)l*Dd;
    const float* postWl = post_W + (size_t)l*12*Dd*Dd;
    const float* postbl = post_b + (size_t)l*Dd;
    const float* outWl  = out_W  + (size_t)l*Dd*Dd;
    const float* outbl  = out_b  + (size_t)l*Dd;

    k_selz<<<512, 256, 0, stream>>>(score, tlist, ctr, thr, out_deg, s1, s2, mxb, mnb, cnt);
    k_degree<<<(Ee + 255)/256, 256, 0, stream>>>(edge_index, score, thr,
                                                 out_deg, node_slot, alist, ctr);
    k_msg<<<MSG_GRID, 128, 0, stream>>>(hidden, edge_index, score, thr, out_deg, node_slot,
                                        slot_deg, flag, tlist, preWl, prebl,
                                        s1, s2, mxb, mnb, cnt, ctr);
    k_post<<<256, 512, 0, stream>>>(cnt, s1, s2, mxb, mnb, slot_deg, postWl, tpart, ctr);
    k_out_resid<<<MAXACT/32, 256, 0, stream>>>(tpart, alist, outWl, outbl, postbl,
                                               hidden, ctr);
    if (l < Ll-1){
      k_score<<<MAXTOUCH/32, 256, 0, stream>>>(hidden, cvec, lin_W, m1_W, m1_b, m2_W, m2_b,
                                               tlist, ctr, score, tlist, 0, nullptr);
    } else {
      k_score<<<1, 256, 0, stream>>>(hidden, cvec, lin_W, m1_W, m1_b, m2_W, m2_b,
                                     tlist, ctr, score, hdr + 4, Bq*NEG, (float*)d_out);
    }
  }
}